// Round 1
// 457.954 us; speedup vs baseline: 1.0876x; 1.0876x over previous
//
#include <hip/hip_runtime.h>
#include <math.h>

// Keep all float arithmetic un-contracted (separate mul/add like the numpy/jax
// f32 reference) so discrete decisions (argmax, top-k order, iou>thr) match.
#pragma clang fp contract(off)

// ---------------- problem constants ----------------
#define BB      8
#define AA      9
#define NCLS    80
#define NTOT    72000      // 57600 + 14400 boxes per image
#define PRE     1000
#define POST    300
#define CAP     4096
#define BCLIP   4.135166556742356f   // log(1000/16)
#define NBLK0   1440       // 72 slabs * 5 cgroups * 4 hw-quarters
#define NBLK1   360        // 72 slabs * 5 cgroups
#define DS1BASE 1843200    // float offset of branch1 delta staging (72*4*6400)

__device__ __constant__ float c_sizes[9] = {16.f,32.f,64.f,20.f,40.f,80.f,24.f,48.f,96.f};

__device__ inline unsigned fkey(float s) {
    unsigned u = __float_as_uint(s);
    return (u & 0x80000000u) ? ~u : (u | 0x80000000u);
}
__device__ inline float unfkey(unsigned u) {
    return __uint_as_float((u & 0x80000000u) ? (u ^ 0x80000000u) : ~u);
}

// ---------------- kernel A: contiguous stream + LDS class-max reduction --------
// Block owns (slab=(b,a), class-group cg, hw-chunk). Channel-sequential inner
// loop: no per-element division, delta-vs-score branch is uniform per channel,
// 8 float4 loads in flight per 4-channel batch.
template<int BR>
__device__ inline void stream_impl(int bx, const float* __restrict__ data,
                                   unsigned long long* __restrict__ partial,
                                   float* __restrict__ dstage,
                                   unsigned long long* lkey)
{
    constexpr int ROWF4 = BR ? 400 : 1600;   // channel row length in float4
    int slab, cg, hwq;
    if (BR == 0) { slab = bx / 20; int r = bx % 20; cg = r / 4; hwq = r % 4; }
    else         { slab = bx / 5;  cg = bx % 5;  hwq = 0; }
    int b = slab / 9, a = slab - (slab / 9) * 9;
    int nch = cg ? 16 : 20;
    int c_first = cg ? (4 + cg * 16) : 0;

    for (int i = threadIdx.x; i < 1600; i += 256) lkey[i] = 0ULL;
    __syncthreads();

    const float4* d4 = (const float4*)data;
    size_t rowbase = (size_t)(b * 756 + a * 84 + c_first) * ROWF4 + hwq * 400;
    float4* ds4 = (float4*)dstage;

    int tid = threadIdx.x;
    int rr2 = tid + 256;               // second strip (only tid<144 active)
    bool s2 = (rr2 < 400);

    for (int c0 = 0; c0 < nch; c0 += 4) {
        float4 v[8];
        #pragma unroll
        for (int u = 0; u < 4; u++) {
            size_t base = rowbase + (size_t)(c0 + u) * ROWF4;
            v[2 * u]     = d4[base + tid];
            v[2 * u + 1] = s2 ? d4[base + rr2] : make_float4(0.f, 0.f, 0.f, 0.f);
        }
        #pragma unroll
        for (int u = 0; u < 4; u++) {
            int ch = c_first + c0 + u;
            if (ch < 4) {              // uniform per u (cg0 batch0 is all-delta)
                size_t di0, di1;
                if (BR) { di0 = (size_t)(DS1BASE / 4) + (size_t)(slab * 4 + ch) * 400 + tid;
                          di1 = di0 + 256; }
                else    { di0 = (size_t)(slab * 4 + ch) * 1600 + hwq * 400 + tid;
                          di1 = di0 + 256; }
                ds4[di0] = v[2 * u];
                if (s2) ds4[di1] = v[2 * u + 1];
            } else {
                unsigned icls = ~(unsigned)(ch - 4);
                float4 x = v[2 * u];
                int cell = tid * 4;
                atomicMax(&lkey[cell + 0], ((unsigned long long)fkey(x.x) << 32) | icls);
                atomicMax(&lkey[cell + 1], ((unsigned long long)fkey(x.y) << 32) | icls);
                atomicMax(&lkey[cell + 2], ((unsigned long long)fkey(x.z) << 32) | icls);
                atomicMax(&lkey[cell + 3], ((unsigned long long)fkey(x.w) << 32) | icls);
                if (s2) {
                    float4 y = v[2 * u + 1];
                    int cell2 = rr2 * 4;
                    atomicMax(&lkey[cell2 + 0], ((unsigned long long)fkey(y.x) << 32) | icls);
                    atomicMax(&lkey[cell2 + 1], ((unsigned long long)fkey(y.y) << 32) | icls);
                    atomicMax(&lkey[cell2 + 2], ((unsigned long long)fkey(y.z) << 32) | icls);
                    atomicMax(&lkey[cell2 + 3], ((unsigned long long)fkey(y.w) << 32) | icls);
                }
            }
        }
    }
    __syncthreads();

    size_t pbase = (size_t)cg * 576000 + (size_t)b * 72000
                 + (BR ? (size_t)(57600 + a * 1600) : (size_t)(a * 6400 + hwq * 1600));
    for (int cell = threadIdx.x; cell < 1600; cell += 256)
        partial[pbase + cell] = lkey[cell];
}

__global__ __launch_bounds__(256) void k_stream(
    const float* __restrict__ data0, const float* __restrict__ data1,
    unsigned long long* __restrict__ partial, float* __restrict__ dstage)
{
    __shared__ unsigned long long lkey[1600];
    int bx = blockIdx.x;
    if (bx < NBLK0) stream_impl<0>(bx, data0, partial, dstage, lkey);
    else            stream_impl<1>(bx - NBLK0, data1, partial, dstage, lkey);
}

// ---------------- kernel B: merge partials + decode + LDS coarse hist ----------
__global__ __launch_bounds__(256) void k_cells(
    const unsigned long long* __restrict__ partial, const float* __restrict__ dstage,
    float* __restrict__ boxes, float* __restrict__ scores, float* __restrict__ cls,
    unsigned* __restrict__ chist)
{
    __shared__ unsigned lh[256];
    int tid = threadIdx.x;
    lh[tid] = 0;
    __syncthreads();

    int b = blockIdx.y;
    int mm = blockIdx.x * 256 + tid;             // pair index (2 cells)
    if (mm < 36000) {
        const ulonglong2* p2 = (const ulonglong2*)partial;
        ulonglong2 best = p2[(size_t)b * 36000 + mm];
        #pragma unroll
        for (int g = 1; g < 5; g++) {
            ulonglong2 v = p2[(size_t)g * 288000 + (size_t)b * 36000 + mm];
            if (v.x > best.x) best.x = v.x;
            if (v.y > best.y) best.y = v.y;
        }
        unsigned long long kk[2] = { best.x, best.y };

        int m0 = mm * 2;
        int a, hw, W, STRIDE;
        size_t dbase;
        if (m0 < 57600) {
            a = m0 / 6400; hw = m0 - a * 6400; W = 80; STRIDE = 8;
            dbase = (size_t)((b * 9 + a) * 4) * 6400 + hw;
        } else {
            int m1 = m0 - 57600;
            a = m1 / 1600; hw = m1 - a * 1600; W = 40; STRIDE = 16;
            dbase = (size_t)DS1BASE + (size_t)((b * 9 + a) * 4) * 1600 + hw;
        }
        size_t cstride = (m0 < 57600) ? 6400 : 1600;
        float2 dx = *(const float2*)(dstage + dbase);
        float2 dy = *(const float2*)(dstage + dbase + cstride);
        float2 dw = *(const float2*)(dstage + dbase + 2 * cstride);
        float2 dh = *(const float2*)(dstage + dbase + 3 * cstride);
        float dxa[2] = {dx.x, dx.y}, dya[2] = {dy.x, dy.y};
        float dwa[2] = {dw.x, dw.y}, dha[2] = {dh.x, dh.y};

        float sz = c_sizes[a];
        size_t o = (size_t)b * NTOT + m0;

        #pragma unroll
        for (int k = 0; k < 2; k++) {
            int hwk = hw + k;
            int h = hwk / W;
            int w = hwk - h * W;
            float cy = (h + 0.5f) * (float)STRIDE;
            float cx = (w + 0.5f) * (float)STRIDE;
            float pcx = dxa[k] * sz + cx;
            float pcy = dya[k] * sz + cy;
            float pw  = expf(fminf(dwa[k], BCLIP)) * sz;
            float ph  = expf(fminf(dha[k], BCLIP)) * sz;
            float x1 = fminf(fmaxf(pcx - 0.5f * pw, 0.f), 640.f);
            float y1 = fminf(fmaxf(pcy - 0.5f * ph, 0.f), 640.f);
            float x2 = fminf(fmaxf(pcx + 0.5f * pw, 0.f), 640.f);
            float y2 = fminf(fmaxf(pcy + 0.5f * ph, 0.f), 640.f);
            ((float4*)boxes)[o + k] = make_float4(x1, y1, x2, y2);
            scores[o + k] = unfkey((unsigned)(kk[k] >> 32));
            cls[o + k]    = (float)(~(unsigned)kk[k]);
            atomicAdd(&lh[(unsigned)(kk[k] >> 56)], 1u);
        }
    }
    __syncthreads();
    if (lh[tid]) atomicAdd(&chist[b * 256 + tid], lh[tid]);
}

// ---------------- kernel C1: coarse scan -> C, cumAbove ----------------
__global__ __launch_bounds__(256) void k_cscan(const unsigned* __restrict__ chist,
                                               unsigned* __restrict__ Cca)
{
    __shared__ unsigned S[256];
    int b = blockIdx.x, tid = threadIdx.x;
    S[tid] = chist[b * 256 + tid];
    __syncthreads();
    for (int off = 1; off < 256; off <<= 1) {   // suffix sum
        unsigned v = S[tid] + ((tid + off < 256) ? S[tid + off] : 0u);
        __syncthreads();
        S[tid] = v;
        __syncthreads();
    }
    if (S[tid] >= (unsigned)PRE && (tid == 255 || S[tid + 1] < (unsigned)PRE)) {
        Cca[b * 2]     = (unsigned)tid;
        Cca[b * 2 + 1] = (tid == 255) ? 0u : S[tid + 1];
    }
}

// ---------------- kernel C2: fine histogram of coarse-bucket-C items ----------
__global__ __launch_bounds__(256) void k_fine(const float* __restrict__ scores,
                                              const unsigned* __restrict__ Cca,
                                              unsigned* __restrict__ fhist)
{
    __shared__ unsigned lh[256];
    int tid = threadIdx.x;
    lh[tid] = 0;
    __syncthreads();
    int b = blockIdx.y;
    unsigned C = Cca[b * 2];
    int m4 = blockIdx.x * 256 + tid;
    if (m4 < NTOT / 4) {
        float sv[4];
        *(float4*)sv = ((const float4*)(scores + (size_t)b * NTOT))[m4];
        #pragma unroll
        for (int k = 0; k < 4; k++) {
            unsigned u = fkey(sv[k]);
            if ((u >> 24) == C) atomicAdd(&lh[(u >> 16) & 0xFF], 1u);
        }
    }
    __syncthreads();
    if (lh[tid]) atomicAdd(&fhist[b * 256 + tid], lh[tid]);
}

// ---------------- kernel C3: fine scan -> 16-bit threshold T ----------------
__global__ __launch_bounds__(256) void k_fthr(const unsigned* __restrict__ fhist,
                                              const unsigned* __restrict__ Cca,
                                              unsigned* __restrict__ T)
{
    __shared__ unsigned S[256];
    int b = blockIdx.x, tid = threadIdx.x;
    unsigned C = Cca[b * 2], ca = Cca[b * 2 + 1];
    S[tid] = fhist[b * 256 + tid];
    __syncthreads();
    for (int off = 1; off < 256; off <<= 1) {
        unsigned v = S[tid] + ((tid + off < 256) ? S[tid + off] : 0u);
        __syncthreads();
        S[tid] = v;
        __syncthreads();
    }
    if (ca + S[tid] >= (unsigned)PRE && (tid == 255 || ca + S[tid + 1] < (unsigned)PRE))
        T[b] = (C << 8) | (unsigned)tid;
}

// ---------------- kernel: compact candidates >= threshold bucket ----------------
__global__ __launch_bounds__(256) void k_compact(const float* __restrict__ scores,
                                                 const unsigned* __restrict__ T,
                                                 unsigned* __restrict__ cnt,
                                                 unsigned long long* __restrict__ cand)
{
    int m4 = blockIdx.x * 256 + threadIdx.x;
    int b = blockIdx.y;
    if (m4 >= NTOT / 4) return;
    float sv[4];
    *(float4*)sv = ((const float4*)(scores + (size_t)b * NTOT))[m4];
    unsigned Tb = T[b];
    #pragma unroll
    for (int k = 0; k < 4; k++) {
        unsigned u = fkey(sv[k]);
        if ((u >> 16) >= Tb) {
            int m = m4 * 4 + k;
            int n;
            if (m < 57600) { int a = m / 6400; int hw = m - a * 6400; n = hw * 9 + a; }
            else { int mm = m - 57600; int a = mm / 1600; int hw = mm - a * 1600; n = 57600 + hw * 9 + a; }
            unsigned pos = atomicAdd(&cnt[b], 1u);
            if (pos < CAP)
                cand[(size_t)b * CAP + pos] = ((unsigned long long)u << 32) | (unsigned)(~(unsigned)n);
        }
    }
}

// ---------------- kernel: per-image bitonic sort (runtime pow2) + gather ------
__global__ __launch_bounds__(1024) void k_sort(
    const unsigned long long* __restrict__ cand, const unsigned* __restrict__ cnt,
    const float* __restrict__ boxes, const float* __restrict__ scores, const float* __restrict__ cls,
    float* __restrict__ sboxes, float* __restrict__ sscores, float* __restrict__ scls)
{
    __shared__ unsigned long long keys[CAP];
    int b = blockIdx.x, tid = threadIdx.x;
    int c = min((int)cnt[b], CAP);
    int P = 1024;
    while (P < c) P <<= 1;
    for (int i = tid; i < P; i += 1024)
        keys[i] = (i < c) ? cand[(size_t)b * CAP + i] : 0ULL;

    for (int k2 = 2; k2 <= P; k2 <<= 1)
        for (int j = k2 >> 1; j > 0; j >>= 1) {
            __syncthreads();
            for (int i = tid; i < P; i += 1024) {
                int l = i ^ j;
                if (l > i) {
                    unsigned long long x = keys[i], y = keys[l];
                    bool up = ((i & k2) == 0);
                    if ((x > y) == up) { keys[i] = y; keys[l] = x; }
                }
            }
        }
    __syncthreads();

    if (tid < PRE) {
        unsigned long long key = keys[P - 1 - tid];       // descending
        int n = (int)~(unsigned)(key & 0xFFFFFFFFu);
        int m;
        if (n < 57600) { int hw = n / 9; int a = n - hw * 9; m = a * 6400 + hw; }
        else { int n2 = n - 57600; int hw = n2 / 9; int a = n2 - hw * 9; m = 57600 + a * 1600 + hw; }
        size_t src = (size_t)b * NTOT + m;
        ((float4*)sboxes)[b * 1024 + tid] = ((const float4*)boxes)[src];
        sscores[b * 1024 + tid] = scores[src];
        scls[b * 1024 + tid] = cls[src];
    }
}

// ---------------- kernel: IN-suppressor bitmask, transposed layout -------------
// maskT[(b*16 + w)*1024 + j] = bits over ii: box i = w*64+ii suppresses box j
// (i < j, iou > NMS_THR, s_i > s_j).  Lane-contiguous in j so k_nms reads are
// coalesced AND need zero cross-lane shuffles: lane j owns its own suppressor
// columns; kept-sets are wave-uniform ballots.
__global__ __launch_bounds__(1024) void k_mask(const float* __restrict__ sboxes,
                                               const float* __restrict__ sscores,
                                               unsigned long long* __restrict__ maskT)
{
    __shared__ float4 bx[64];
    __shared__ float  sl[64];
    int b = blockIdx.y, w = blockIdx.x, tid = threadIdx.x;
    if (tid < 64) {
        int i = w * 64 + tid;
        bx[tid] = ((const float4*)sboxes)[b * 1024 + i];
        sl[tid] = sscores[b * 1024 + i];
    }
    __syncthreads();
    int j = tid;
    unsigned long long* dst = &maskT[((size_t)(b * 16) + w) * 1024 + j];
    if (j >= PRE || w * 64 >= j) { *dst = 0ULL; return; }

    float4 bj = ((const float4*)sboxes)[b * 1024 + j];
    float sj = sscores[b * 1024 + j];
    float areaj = (bj.z - bj.x) * (bj.w - bj.y);
    unsigned long long bits = 0;
    int iend = min(64, j - w * 64);          // suppressors must have i < j
    for (int ii = 0; ii < iend; ii++) {
        float4 bi = bx[ii];
        float ix1 = fmaxf(bi.x, bj.x), iy1 = fmaxf(bi.y, bj.y);
        float ix2 = fminf(bi.z, bj.z), iy2 = fminf(bi.w, bj.w);
        float iw = fmaxf(ix2 - ix1, 0.f), ih = fmaxf(iy2 - iy1, 0.f);
        float inter = iw * ih;
        float areai = (bi.z - bi.x) * (bi.w - bi.y);
        float iou = inter / (areai + areaj - inter + 1e-9f);
        if (iou > 0.5f && sl[ii] > sj) bits |= 1ull << ii;
    }
    *dst = bits;
}

// ---------------- kernel: shuffle-free greedy NMS + output (1 wave / image) ---
// Exact greedy order: chunks c=0..15 resolved sequentially; within a chunk the
// first-alive box is kept (uniform s_ff1 on the ballot) and each lane kills
// itself via its own column bit — serial chain is SALU/ballot only, no
// ds_bpermute anywhere.
__global__ __launch_bounds__(64) void k_nms(const unsigned long long* __restrict__ maskT,
                                            const float* __restrict__ sboxes,
                                            const float* __restrict__ sscores,
                                            const float* __restrict__ scls,
                                            float* __restrict__ out)
{
    int b = blockIdx.x, lane = threadIdx.x;
    const unsigned long long* base = maskT + (size_t)b * 16 * 1024;

    // per-lane validity bit for each chunk (bit c = box c*64+lane valid)
    unsigned validbits = 0;
    #pragma unroll
    for (int c = 0; c < 16; c++) {
        int r = c * 64 + lane;
        bool v = false;
        if (r < PRE) {
            float sc = sscores[b * 1024 + r];
            float4 bbx = ((const float4*)sboxes)[b * 1024 + r];
            v = (sc >= 0.05f) && (bbx.x < bbx.z) && (bbx.y < bbx.w);
        }
        validbits |= (v ? 1u : 0u) << c;
    }

    unsigned long long keptw[16];
    #pragma unroll
    for (int c = 0; c < 16; c++) {
        // lane j = box c*64+lane: load its suppressor columns for chunks 0..c.
        // Loads are independent of keptw -> batched, one vmcnt wait per chunk.
        unsigned long long acc = 0, col = 0;
        #pragma unroll
        for (int w = 0; w <= c; w++) {
            unsigned long long m = base[(w << 10) + c * 64 + lane];
            if (w < c) acc |= m & keptw[w];   // suppressed by an earlier kept box?
            else       col = m;               // intra-chunk suppressor column
        }
        bool alive = (((validbits >> c) & 1u) != 0u) && (acc == 0ULL);

        unsigned long long ab = __ballot(alive);
        unsigned long long kw = 0;
        while (ab) {
            int f = __ffsll((unsigned long long)ab) - 1;   // first alive -> kept
            kw |= 1ULL << f;
            alive = alive && (lane != f) && (((col >> f) & 1ULL) == 0ULL);
            ab = __ballot(alive);
        }
        keptw[c] = kw;
    }

    __shared__ unsigned long long kws[16];
    __shared__ int pfx[17];
    if (lane == 0) {
        int s = 0;
        #pragma unroll
        for (int w = 0; w < 16; w++) {
            kws[w] = keptw[w];
            pfx[w] = s;
            s += __popcll(keptw[w]);
        }
        pfx[16] = s;
    }
    __syncthreads();
    int nk = pfx[16];

    float* ob = out;                       // [8][300][4]
    float* os = out + BB * POST * 4;       // [8][300]
    float* oc = os + BB * POST;            // [8][300]

    for (int r = lane; r < PRE; r += 64) {
        int w = r >> 6;
        unsigned long long kw = kws[w];
        if ((kw >> (r & 63)) & 1ULL) {
            int rank = pfx[w] + __popcll(kw & ((1ULL << (r & 63)) - 1ULL));
            if (rank < POST) {
                ((float4*)ob)[b * POST + rank] = ((const float4*)sboxes)[b * 1024 + r];
                os[b * POST + rank] = sscores[b * 1024 + r];
                oc[b * POST + rank] = scls[b * 1024 + r];
            }
        }
    }
    for (int p = nk + lane; p < POST; p += 64) {
        ((float4*)ob)[b * POST + p] = make_float4(0.f, 0.f, 0.f, 0.f);
        os[b * POST + p] = 0.f;
        oc[b * POST + p] = 0.f;
    }
}

// ---------------- launch ----------------
extern "C" void kernel_launch(void* const* d_in, const int* in_sizes, int n_in,
                              void* d_out, int out_size, void* d_ws, size_t ws_size,
                              hipStream_t stream)
{
    const float* data0 = (const float*)d_in[0];
    const float* data1 = (const float*)d_in[2];
    for (int i = 0; i < n_in; i++) {
        if (in_sizes[i] == 8 * 756 * 6400) data0 = (const float*)d_in[i];
        else if (in_sizes[i] == 8 * 756 * 1600) data1 = (const float*)d_in[i];
    }

    char* ws = (char*)d_ws;
    size_t off = 0;
    auto alloc = [&](size_t bytes) -> char* {
        char* p = ws + off;
        off = (off + bytes + 255) & ~(size_t)255;
        return p;
    };

    float* boxes   = (float*)alloc((size_t)BB * NTOT * 4 * 4);
    float* scores  = (float*)alloc((size_t)BB * NTOT * 4);
    float* cls     = (float*)alloc((size_t)BB * NTOT * 4);
    // zero-init group (contiguous): cnt(256B pad) + chist(8K) + fhist(8K)
    unsigned* cnt   = (unsigned*)alloc(BB * 4);
    unsigned* chist = (unsigned*)alloc(BB * 256 * 4);
    unsigned* fhist = (unsigned*)alloc(BB * 256 * 4);
    unsigned* Cca  = (unsigned*)alloc(BB * 2 * 4);
    unsigned* T    = (unsigned*)alloc(BB * 4);
    unsigned long long* cand = (unsigned long long*)alloc((size_t)BB * CAP * 8);
    float* sboxes  = (float*)alloc((size_t)BB * 1024 * 4 * 4);
    float* sscores = (float*)alloc((size_t)BB * 1024 * 4);
    float* scls    = (float*)alloc((size_t)BB * 1024 * 4);
    unsigned long long* maskT = (unsigned long long*)alloc((size_t)BB * 16 * 1024 * 8);
    unsigned long long* partial = (unsigned long long*)alloc((size_t)5 * 576000 * 8);
    float* dstage  = (float*)alloc((size_t)(DS1BASE + 72 * 4 * 1600) * 4);

    (void)hipMemsetAsync(cnt, 0, 256 + 2 * (size_t)BB * 256 * 4, stream);

    k_stream<<<NBLK0 + NBLK1, 256, 0, stream>>>(data0, data1, partial, dstage);

    dim3 gc(141, BB);
    k_cells<<<gc, 256, 0, stream>>>(partial, dstage, boxes, scores, cls, chist);

    k_cscan<<<BB, 256, 0, stream>>>(chist, Cca);
    dim3 gf((NTOT / 4 + 255) / 256, BB);
    k_fine<<<gf, 256, 0, stream>>>(scores, Cca, fhist);
    k_fthr<<<BB, 256, 0, stream>>>(fhist, Cca, T);

    k_compact<<<gf, 256, 0, stream>>>(scores, T, cnt, cand);

    k_sort<<<BB, 1024, 0, stream>>>(cand, cnt, boxes, scores, cls, sboxes, sscores, scls);

    dim3 g5(16, BB);
    k_mask<<<g5, 1024, 0, stream>>>(sboxes, sscores, maskT);

    k_nms<<<BB, 64, 0, stream>>>(maskT, sboxes, sscores, scls, (float*)d_out);
}

// Round 2
// 438.556 us; speedup vs baseline: 1.1357x; 1.0442x over previous
//
#include <hip/hip_runtime.h>
#include <math.h>

// Keep all float arithmetic un-contracted (separate mul/add like the numpy/jax
// f32 reference) so discrete decisions (argmax, top-k order, iou>thr) match.
#pragma clang fp contract(off)

// ---------------- problem constants ----------------
#define BB      8
#define AA      9
#define NCLS    80
#define NTOT    72000      // 57600 + 14400 boxes per image
#define PRE     1000
#define POST    300
#define CAP     4096
#define BCLIP   4.135166556742356f   // log(1000/16)

__device__ __constant__ float c_sizes[9] = {16.f,32.f,64.f,20.f,40.f,80.f,24.f,48.f,96.f};

__device__ inline unsigned fkey(float s) {
    unsigned u = __float_as_uint(s);
    return (u & 0x80000000u) ? ~u : (u | 0x80000000u);
}

// ---------------- kernel A (fused): stream + register argmax + decode ---------
// One block owns ALL 84 channels of a 800-cell chunk -> each thread owns its 4
// cells exclusively: class-max is a register (best, argmax) pair, strict-> update
// (first-max wins = jnp.argmax). Deltas stay in registers; decode + box/score/
// cls writes happen here. No partial buffers, no dstage, no LDS atomics.
template<int BR>
__device__ inline void fused_impl(int bx, const float* __restrict__ data,
    float* __restrict__ boxes, float* __restrict__ scores, float* __restrict__ cls,
    unsigned* __restrict__ chist, unsigned* lh)
{
    constexpr int ROWF4  = BR ? 400 : 1600;   // channel row length in float4
    constexpr int W      = BR ? 40 : 80;
    constexpr int STRIDE = BR ? 16 : 8;
    constexpr int NQ     = BR ? 2 : 8;        // chunks per row (200 f4 each)

    int slab = bx / NQ;
    int q    = bx - slab * NQ;
    int b = slab / 9, a = slab - (slab / 9) * 9;
    int tid = threadIdx.x;
    bool act = tid < 200;

    const float4* d4 = (const float4*)data;
    size_t rowbase = (size_t)(b * 756 + a * 84) * ROWF4 + q * 200;

    if (act) {
        // deltas (channels 0..3) -> registers
        float4 del[4];
        #pragma unroll
        for (int u = 0; u < 4; u++)
            del[u] = d4[rowbase + (size_t)u * ROWF4 + tid];

        float best[4];
        int   bc[4];
        #pragma unroll
        for (int k = 0; k < 4; k++) { best[k] = -INFINITY; bc[k] = 0; }

        // class channels 4..83, batches of 8 (8 loads in flight)
        for (int c0 = 4; c0 < 84; c0 += 8) {
            float4 v[8];
            #pragma unroll
            for (int u = 0; u < 8; u++)
                v[u] = d4[rowbase + (size_t)(c0 + u) * ROWF4 + tid];
            #pragma unroll
            for (int u = 0; u < 8; u++) {
                int c = c0 + u - 4;
                float s0[4];
                *(float4*)s0 = v[u];
                #pragma unroll
                for (int k = 0; k < 4; k++)
                    if (s0[k] > best[k]) { best[k] = s0[k]; bc[k] = c; }
            }
        }

        // decode + write
        float sz = c_sizes[a];
        float dx[4], dy[4], dwv[4], dhv[4];
        *(float4*)dx  = del[0];
        *(float4*)dy  = del[1];
        *(float4*)dwv = del[2];
        *(float4*)dhv = del[3];

        int ml0 = q * 800 + tid * 4;
        size_t obase = (size_t)b * NTOT + (BR ? (57600 + a * 1600) : (a * 6400));

        #pragma unroll
        for (int k = 0; k < 4; k++) {
            int hw = ml0 + k;
            int h = hw / W, w = hw - h * W;
            float cy = (h + 0.5f) * (float)STRIDE;
            float cx = (w + 0.5f) * (float)STRIDE;
            float pcx = dx[k] * sz + cx;
            float pcy = dy[k] * sz + cy;
            float pw  = expf(fminf(dwv[k], BCLIP)) * sz;
            float ph  = expf(fminf(dhv[k], BCLIP)) * sz;
            float x1 = fminf(fmaxf(pcx - 0.5f * pw, 0.f), 640.f);
            float y1 = fminf(fmaxf(pcy - 0.5f * ph, 0.f), 640.f);
            float x2 = fminf(fmaxf(pcx + 0.5f * pw, 0.f), 640.f);
            float y2 = fminf(fmaxf(pcy + 0.5f * ph, 0.f), 640.f);
            size_t o = obase + hw;
            ((float4*)boxes)[o] = make_float4(x1, y1, x2, y2);
            scores[o] = best[k];
            cls[o]    = (float)bc[k];
            atomicAdd(&lh[fkey(best[k]) >> 24], 1u);
        }
    }
    __syncthreads();
    if (lh[tid]) atomicAdd(&chist[b * 256 + tid], lh[tid]);
}

__global__ __launch_bounds__(256) void k_fused(
    const float* __restrict__ data0, const float* __restrict__ data1,
    float* __restrict__ boxes, float* __restrict__ scores, float* __restrict__ cls,
    unsigned* __restrict__ chist)
{
    __shared__ unsigned lh[256];
    lh[threadIdx.x] = 0;
    __syncthreads();
    int bx = blockIdx.x;
    if (bx < 576) fused_impl<0>(bx, data0, boxes, scores, cls, chist, lh);
    else          fused_impl<1>(bx - 576, data1, boxes, scores, cls, chist, lh);
}

// ---------------- kernel C2: coarse scan (folded) + fine histogram ------------
__global__ __launch_bounds__(256) void k_fine(const float* __restrict__ scores,
                                              const unsigned* __restrict__ chist,
                                              unsigned* __restrict__ fhist)
{
    __shared__ unsigned S[256];
    __shared__ unsigned lh[256];
    __shared__ unsigned sC;
    int tid = threadIdx.x, b = blockIdx.y;
    S[tid]  = chist[b * 256 + tid];
    lh[tid] = 0;
    __syncthreads();
    for (int off = 1; off < 256; off <<= 1) {   // suffix sum
        unsigned v = S[tid] + ((tid + off < 256) ? S[tid + off] : 0u);
        __syncthreads();
        S[tid] = v;
        __syncthreads();
    }
    if (S[tid] >= (unsigned)PRE && (tid == 255 || S[tid + 1] < (unsigned)PRE)) sC = tid;
    __syncthreads();
    unsigned C = sC;

    int m4 = blockIdx.x * 256 + tid;
    if (m4 < NTOT / 4) {
        float sv[4];
        *(float4*)sv = ((const float4*)(scores + (size_t)b * NTOT))[m4];
        #pragma unroll
        for (int k = 0; k < 4; k++) {
            unsigned u = fkey(sv[k]);
            if ((u >> 24) == C) atomicAdd(&lh[(u >> 16) & 0xFF], 1u);
        }
    }
    __syncthreads();
    if (lh[tid]) atomicAdd(&fhist[b * 256 + tid], lh[tid]);
}

// ---------------- kernel: both scans (folded) + compact >= threshold ----------
__global__ __launch_bounds__(256) void k_compact(const float* __restrict__ scores,
                                                 const unsigned* __restrict__ chist,
                                                 const unsigned* __restrict__ fhist,
                                                 unsigned* __restrict__ cnt,
                                                 unsigned long long* __restrict__ cand)
{
    __shared__ unsigned S[256];
    __shared__ unsigned sC, sCa, sT;
    int tid = threadIdx.x, b = blockIdx.y;

    S[tid] = chist[b * 256 + tid];
    __syncthreads();
    for (int off = 1; off < 256; off <<= 1) {
        unsigned v = S[tid] + ((tid + off < 256) ? S[tid + off] : 0u);
        __syncthreads();
        S[tid] = v;
        __syncthreads();
    }
    if (S[tid] >= (unsigned)PRE && (tid == 255 || S[tid + 1] < (unsigned)PRE)) {
        sC  = tid;
        sCa = (tid == 255) ? 0u : S[tid + 1];
    }
    __syncthreads();
    unsigned C = sC, ca = sCa;
    S[tid] = fhist[b * 256 + tid];
    __syncthreads();
    for (int off = 1; off < 256; off <<= 1) {
        unsigned v = S[tid] + ((tid + off < 256) ? S[tid + off] : 0u);
        __syncthreads();
        S[tid] = v;
        __syncthreads();
    }
    if (ca + S[tid] >= (unsigned)PRE && (tid == 255 || ca + S[tid + 1] < (unsigned)PRE))
        sT = (C << 8) | (unsigned)tid;
    __syncthreads();
    unsigned Tb = sT;

    int m4 = blockIdx.x * 256 + tid;
    if (m4 >= NTOT / 4) return;
    float sv[4];
    *(float4*)sv = ((const float4*)(scores + (size_t)b * NTOT))[m4];
    #pragma unroll
    for (int k = 0; k < 4; k++) {
        unsigned u = fkey(sv[k]);
        if ((u >> 16) >= Tb) {
            int m = m4 * 4 + k;
            int n;
            if (m < 57600) { int a = m / 6400; int hw = m - a * 6400; n = hw * 9 + a; }
            else { int mm = m - 57600; int a = mm / 1600; int hw = mm - a * 1600; n = 57600 + hw * 9 + a; }
            unsigned pos = atomicAdd(&cnt[b], 1u);
            if (pos < CAP)
                cand[(size_t)b * CAP + pos] = ((unsigned long long)u << 32) | (unsigned)(~(unsigned)n);
        }
    }
}

// ---------------- kernel: per-image bitonic sort (runtime pow2) + gather ------
__global__ __launch_bounds__(1024) void k_sort(
    const unsigned long long* __restrict__ cand, const unsigned* __restrict__ cnt,
    const float* __restrict__ boxes, const float* __restrict__ scores, const float* __restrict__ cls,
    float* __restrict__ sboxes, float* __restrict__ sscores, float* __restrict__ scls)
{
    __shared__ unsigned long long keys[CAP];
    int b = blockIdx.x, tid = threadIdx.x;
    int c = min((int)cnt[b], CAP);
    int P = 1024;
    while (P < c) P <<= 1;
    for (int i = tid; i < P; i += 1024)
        keys[i] = (i < c) ? cand[(size_t)b * CAP + i] : 0ULL;

    for (int k2 = 2; k2 <= P; k2 <<= 1)
        for (int j = k2 >> 1; j > 0; j >>= 1) {
            __syncthreads();
            for (int i = tid; i < P; i += 1024) {
                int l = i ^ j;
                if (l > i) {
                    unsigned long long x = keys[i], y = keys[l];
                    bool up = ((i & k2) == 0);
                    if ((x > y) == up) { keys[i] = y; keys[l] = x; }
                }
            }
        }
    __syncthreads();

    if (tid < PRE) {
        unsigned long long key = keys[P - 1 - tid];       // descending
        int n = (int)~(unsigned)(key & 0xFFFFFFFFu);
        int m;
        if (n < 57600) { int hw = n / 9; int a = n - hw * 9; m = a * 6400 + hw; }
        else { int n2 = n - 57600; int hw = n2 / 9; int a = n2 - hw * 9; m = 57600 + a * 1600 + hw; }
        size_t src = (size_t)b * NTOT + m;
        ((float4*)sboxes)[b * 1024 + tid] = ((const float4*)boxes)[src];
        sscores[b * 1024 + tid] = scores[src];
        scls[b * 1024 + tid] = cls[src];
    }
}

// ---------------- kernel: IN-suppressor bitmask, transposed layout -------------
// maskT[(b*16 + w)*1024 + j] = bits over ii: box i = w*64+ii suppresses box j
// (i < j, iou > NMS_THR, s_i > s_j).  Lane-contiguous in j: coalesced reads and
// zero cross-lane shuffles in k_nms.
__global__ __launch_bounds__(1024) void k_mask(const float* __restrict__ sboxes,
                                               const float* __restrict__ sscores,
                                               unsigned long long* __restrict__ maskT)
{
    __shared__ float4 bx[64];
    __shared__ float  sl[64];
    int b = blockIdx.y, w = blockIdx.x, tid = threadIdx.x;
    if (tid < 64) {
        int i = w * 64 + tid;
        bx[tid] = ((const float4*)sboxes)[b * 1024 + i];
        sl[tid] = sscores[b * 1024 + i];
    }
    __syncthreads();
    int j = tid;
    unsigned long long* dst = &maskT[((size_t)(b * 16) + w) * 1024 + j];
    if (j >= PRE || w * 64 >= j) { *dst = 0ULL; return; }

    float4 bj = ((const float4*)sboxes)[b * 1024 + j];
    float sj = sscores[b * 1024 + j];
    float areaj = (bj.z - bj.x) * (bj.w - bj.y);
    unsigned long long bits = 0;
    int iend = min(64, j - w * 64);          // suppressors must have i < j
    for (int ii = 0; ii < iend; ii++) {
        float4 bi = bx[ii];
        float ix1 = fmaxf(bi.x, bj.x), iy1 = fmaxf(bi.y, bj.y);
        float ix2 = fminf(bi.z, bj.z), iy2 = fminf(bi.w, bj.w);
        float iw = fmaxf(ix2 - ix1, 0.f), ih = fmaxf(iy2 - iy1, 0.f);
        float inter = iw * ih;
        float areai = (bi.z - bi.x) * (bi.w - bi.y);
        float iou = inter / (areai + areaj - inter + 1e-9f);
        if (iou > 0.5f && sl[ii] > sj) bits |= 1ull << ii;
    }
    *dst = bits;
}

// ---------------- kernel: shuffle-free greedy NMS + output (1 wave / image) ---
__global__ __launch_bounds__(64) void k_nms(const unsigned long long* __restrict__ maskT,
                                            const float* __restrict__ sboxes,
                                            const float* __restrict__ sscores,
                                            const float* __restrict__ scls,
                                            float* __restrict__ out)
{
    int b = blockIdx.x, lane = threadIdx.x;
    const unsigned long long* base = maskT + (size_t)b * 16 * 1024;

    // per-lane validity bit for each chunk (bit c = box c*64+lane valid)
    unsigned validbits = 0;
    #pragma unroll
    for (int c = 0; c < 16; c++) {
        int r = c * 64 + lane;
        bool v = false;
        if (r < PRE) {
            float sc = sscores[b * 1024 + r];
            float4 bbx = ((const float4*)sboxes)[b * 1024 + r];
            v = (sc >= 0.05f) && (bbx.x < bbx.z) && (bbx.y < bbx.w);
        }
        validbits |= (v ? 1u : 0u) << c;
    }

    unsigned long long keptw[16];
    #pragma unroll
    for (int c = 0; c < 16; c++) {
        unsigned long long acc = 0, col = 0;
        #pragma unroll
        for (int w = 0; w <= c; w++) {
            unsigned long long m = base[(w << 10) + c * 64 + lane];
            if (w < c) acc |= m & keptw[w];   // suppressed by an earlier kept box?
            else       col = m;               // intra-chunk suppressor column
        }
        bool alive = (((validbits >> c) & 1u) != 0u) && (acc == 0ULL);

        unsigned long long ab = __ballot(alive);
        unsigned long long kw = 0;
        while (ab) {
            int f = __ffsll((unsigned long long)ab) - 1;   // first alive -> kept
            kw |= 1ULL << f;
            alive = alive && (lane != f) && (((col >> f) & 1ULL) == 0ULL);
            ab = __ballot(alive);
        }
        keptw[c] = kw;
    }

    __shared__ unsigned long long kws[16];
    __shared__ int pfx[17];
    if (lane == 0) {
        int s = 0;
        #pragma unroll
        for (int w = 0; w < 16; w++) {
            kws[w] = keptw[w];
            pfx[w] = s;
            s += __popcll(keptw[w]);
        }
        pfx[16] = s;
    }
    __syncthreads();
    int nk = pfx[16];

    float* ob = out;                       // [8][300][4]
    float* os = out + BB * POST * 4;       // [8][300]
    float* oc = os + BB * POST;            // [8][300]

    for (int r = lane; r < PRE; r += 64) {
        int w = r >> 6;
        unsigned long long kw = kws[w];
        if ((kw >> (r & 63)) & 1ULL) {
            int rank = pfx[w] + __popcll(kw & ((1ULL << (r & 63)) - 1ULL));
            if (rank < POST) {
                ((float4*)ob)[b * POST + rank] = ((const float4*)sboxes)[b * 1024 + r];
                os[b * POST + rank] = sscores[b * 1024 + r];
                oc[b * POST + rank] = scls[b * 1024 + r];
            }
        }
    }
    for (int p = nk + lane; p < POST; p += 64) {
        ((float4*)ob)[b * POST + p] = make_float4(0.f, 0.f, 0.f, 0.f);
        os[b * POST + p] = 0.f;
        oc[b * POST + p] = 0.f;
    }
}

// ---------------- launch ----------------
extern "C" void kernel_launch(void* const* d_in, const int* in_sizes, int n_in,
                              void* d_out, int out_size, void* d_ws, size_t ws_size,
                              hipStream_t stream)
{
    const float* data0 = (const float*)d_in[0];
    const float* data1 = (const float*)d_in[2];
    for (int i = 0; i < n_in; i++) {
        if (in_sizes[i] == 8 * 756 * 6400) data0 = (const float*)d_in[i];
        else if (in_sizes[i] == 8 * 756 * 1600) data1 = (const float*)d_in[i];
    }

    char* ws = (char*)d_ws;
    size_t off = 0;
    auto alloc = [&](size_t bytes) -> char* {
        char* p = ws + off;
        off = (off + bytes + 255) & ~(size_t)255;
        return p;
    };

    float* boxes   = (float*)alloc((size_t)BB * NTOT * 4 * 4);
    float* scores  = (float*)alloc((size_t)BB * NTOT * 4);
    float* cls     = (float*)alloc((size_t)BB * NTOT * 4);
    // zero-init group (contiguous): cnt(256B pad) + chist(8K) + fhist(8K)
    unsigned* cnt   = (unsigned*)alloc(BB * 4);
    unsigned* chist = (unsigned*)alloc(BB * 256 * 4);
    unsigned* fhist = (unsigned*)alloc(BB * 256 * 4);
    unsigned long long* cand = (unsigned long long*)alloc((size_t)BB * CAP * 8);
    float* sboxes  = (float*)alloc((size_t)BB * 1024 * 4 * 4);
    float* sscores = (float*)alloc((size_t)BB * 1024 * 4);
    float* scls    = (float*)alloc((size_t)BB * 1024 * 4);
    unsigned long long* maskT = (unsigned long long*)alloc((size_t)BB * 16 * 1024 * 8);

    (void)hipMemsetAsync(cnt, 0, 256 + 2 * (size_t)BB * 256 * 4, stream);

    k_fused<<<720, 256, 0, stream>>>(data0, data1, boxes, scores, cls, chist);

    dim3 gf((NTOT / 4 + 255) / 256, BB);
    k_fine<<<gf, 256, 0, stream>>>(scores, chist, fhist);

    k_compact<<<gf, 256, 0, stream>>>(scores, chist, fhist, cnt, cand);

    k_sort<<<BB, 1024, 0, stream>>>(cand, cnt, boxes, scores, cls, sboxes, sscores, scls);

    dim3 g5(16, BB);
    k_mask<<<g5, 1024, 0, stream>>>(sboxes, sscores, maskT);

    k_nms<<<BB, 64, 0, stream>>>(maskT, sboxes, sscores, scls, (float*)d_out);
}